// Round 1
// baseline (1616.646 us; speedup 1.0000x reference)
//
#include <hip/hip_runtime.h>
#include <hip/hip_bf16.h>
#include <cstddef>

#define N_NODES 100000
#define N_EDGES 1600000
#define NFEAT 512
#define NHID 256
#define NCLASS 128
#define K_HOPS 5
#define ALPHA 0.1f

// ---------------------------------------------------------------------------
// CSR build: histogram -> scan -> scatter
// ---------------------------------------------------------------------------

__global__ void count_kernel(const int* __restrict__ dst, int* __restrict__ counts, int E) {
    int i = blockIdx.x * blockDim.x + threadIdx.x;
    if (i < E) atomicAdd(&counts[dst[i]], 1);
}

// Single-block exclusive scan over counts[n] -> row_ptr[n+1], and fill[i]=row_ptr[i].
// counts and fill may alias (read-before-write per index within one thread's chunk).
__global__ __launch_bounds__(1024) void scan_kernel(const int* __restrict__ counts,
                                                    int* __restrict__ row_ptr,
                                                    int* __restrict__ fill, int n) {
    __shared__ int part[1024];
    int tid = threadIdx.x;
    int chunk = (n + 1023) / 1024;
    int beg = tid * chunk;
    int end = beg + chunk; if (end > n) end = n;
    int s = 0;
    for (int i = beg; i < end; ++i) s += counts[i];
    part[tid] = s;
    __syncthreads();
    // Hillis-Steele inclusive scan
    for (int off = 1; off < 1024; off <<= 1) {
        int v = (tid >= off) ? part[tid - off] : 0;
        __syncthreads();
        part[tid] += v;
        __syncthreads();
    }
    int pre = (tid == 0) ? 0 : part[tid - 1];
    for (int i = beg; i < end; ++i) {
        int c = counts[i];           // read BEFORE overwriting (fill may alias counts)
        row_ptr[i] = pre;
        fill[i] = pre;
        pre += c;
    }
    if (tid == 1023) row_ptr[n] = part[1023];
}

__global__ void scatter_kernel(const int* __restrict__ src, const int* __restrict__ dst,
                               const float* __restrict__ w, int* __restrict__ fill,
                               int* __restrict__ col, float* __restrict__ wsorted, int E) {
    int i = blockIdx.x * blockDim.x + threadIdx.x;
    if (i < E) {
        int d = dst[i];
        int pos = atomicAdd(&fill[d], 1);
        col[pos] = src[i];
        wsorted[pos] = w[i];
    }
}

// ---------------------------------------------------------------------------
// f32 tiled GEMM: C[M,N] = act(A[M,K] @ B[K,N] + bias)
// 64x64 tile, BK=16, 256 threads, 4x4 microtile
// ---------------------------------------------------------------------------
#define GBM 64
#define GBN 64
#define GBK 16

__global__ __launch_bounds__(256) void gemm_bias(const float* __restrict__ A,
                                                 const float* __restrict__ B,
                                                 const float* __restrict__ bias,
                                                 float* __restrict__ C,
                                                 int M, int N, int K, int relu) {
    __shared__ float As[GBK][GBM];   // [k][m]
    __shared__ float Bs[GBK][GBN];   // [k][n]
    int tid = threadIdx.x;
    int tx = tid & 15, ty = tid >> 4;
    int row0 = blockIdx.y * GBM, col0 = blockIdx.x * GBN;

    int la_r = tid >> 2;            // 0..63
    int la_k = (tid & 3) * 4;       // 0,4,8,12
    int lb_kk = tid >> 4;           // 0..15
    int lb_c  = (tid & 15) * 4;     // 0..60

    float acc[4][4] = {};

    for (int k0 = 0; k0 < K; k0 += GBK) {
        int ar = row0 + la_r;
        float4 av;
        if (ar < M) av = *(const float4*)&A[(size_t)ar * K + k0 + la_k];
        else        av = make_float4(0.f, 0.f, 0.f, 0.f);
        As[la_k + 0][la_r] = av.x;
        As[la_k + 1][la_r] = av.y;
        As[la_k + 2][la_r] = av.z;
        As[la_k + 3][la_r] = av.w;
        float4 bv = *(const float4*)&B[(size_t)(k0 + lb_kk) * N + col0 + lb_c];
        *(float4*)&Bs[lb_kk][lb_c] = bv;
        __syncthreads();
#pragma unroll
        for (int kk = 0; kk < GBK; ++kk) {
            float4 a = *(const float4*)&As[kk][ty * 4];
            float4 b = *(const float4*)&Bs[kk][tx * 4];
            float aa[4] = {a.x, a.y, a.z, a.w};
            float bb[4] = {b.x, b.y, b.z, b.w};
#pragma unroll
            for (int i = 0; i < 4; ++i)
#pragma unroll
                for (int j = 0; j < 4; ++j)
                    acc[i][j] = fmaf(aa[i], bb[j], acc[i][j]);
        }
        __syncthreads();
    }

    float4 bv = *(const float4*)&bias[col0 + tx * 4];
    float bb[4] = {bv.x, bv.y, bv.z, bv.w};
#pragma unroll
    for (int i = 0; i < 4; ++i) {
        int r = row0 + ty * 4 + i;
        if (r < M) {
            float4 o;
            o.x = acc[i][0] + bb[0];
            o.y = acc[i][1] + bb[1];
            o.z = acc[i][2] + bb[2];
            o.w = acc[i][3] + bb[3];
            if (relu) {
                o.x = fmaxf(o.x, 0.f); o.y = fmaxf(o.y, 0.f);
                o.z = fmaxf(o.z, 0.f); o.w = fmaxf(o.w, 0.f);
            }
            *(float4*)&C[(size_t)r * N + col0 + tx * 4] = o;
        }
    }
}

// ---------------------------------------------------------------------------
// One propagation hop (pull over CSR-by-dst): one wave per node, float2/lane
// ---------------------------------------------------------------------------
__global__ __launch_bounds__(256) void hop_kernel(const float* __restrict__ carry,
                                                  const float* __restrict__ x0,
                                                  const int* __restrict__ rp,
                                                  const int* __restrict__ col,
                                                  const float* __restrict__ ew,
                                                  float* __restrict__ out, int nnodes) {
    int node = blockIdx.x * 4 + (threadIdx.x >> 6);
    if (node >= nnodes) return;
    int lane = threadIdx.x & 63;
    size_t base = (size_t)node * NCLASS + lane * 2;
    int e0 = rp[node], e1 = rp[node + 1];
    float ax = 0.f, ay = 0.f, bx = 0.f, by = 0.f;
    int e = e0;
    for (; e + 1 < e1; e += 2) {
        int s0 = col[e], s1 = col[e + 1];
        float w0 = ew[e], w1 = ew[e + 1];
        float2 v0 = *(const float2*)&carry[(size_t)s0 * NCLASS + lane * 2];
        float2 v1 = *(const float2*)&carry[(size_t)s1 * NCLASS + lane * 2];
        ax = fmaf(w0, v0.x, ax); ay = fmaf(w0, v0.y, ay);
        bx = fmaf(w1, v1.x, bx); by = fmaf(w1, v1.y, by);
    }
    if (e < e1) {
        int s0 = col[e];
        float w0 = ew[e];
        float2 v0 = *(const float2*)&carry[(size_t)s0 * NCLASS + lane * 2];
        ax = fmaf(w0, v0.x, ax); ay = fmaf(w0, v0.y, ay);
    }
    float2 xv = *(const float2*)&x0[base];
    float2 o;
    o.x = (1.f - ALPHA) * (ax + bx) + ALPHA * xv.x;
    o.y = (1.f - ALPHA) * (ay + by) + ALPHA * xv.y;
    *(float2*)&out[base] = o;
}

// ---------------------------------------------------------------------------
// log_softmax over rows of 128: one wave per node
// ---------------------------------------------------------------------------
__global__ __launch_bounds__(256) void logsoftmax_kernel(const float* __restrict__ in,
                                                         float* __restrict__ out, int nnodes) {
    int node = blockIdx.x * 4 + (threadIdx.x >> 6);
    if (node >= nnodes) return;
    int lane = threadIdx.x & 63;
    size_t base = (size_t)node * NCLASS + lane * 2;
    float2 v = *(const float2*)&in[base];
    float m = fmaxf(v.x, v.y);
#pragma unroll
    for (int off = 32; off; off >>= 1) m = fmaxf(m, __shfl_xor(m, off, 64));
    float s = expf(v.x - m) + expf(v.y - m);
#pragma unroll
    for (int off = 32; off; off >>= 1) s += __shfl_xor(s, off, 64);
    float l = m + logf(s);
    float2 o; o.x = v.x - l; o.y = v.y - l;
    *(float2*)&out[base] = o;
}

// ---------------------------------------------------------------------------

extern "C" void kernel_launch(void* const* d_in, const int* in_sizes, int n_in,
                              void* d_out, int out_size, void* d_ws, size_t ws_size,
                              hipStream_t stream) {
    const float* x   = (const float*)d_in[0];
    const int*   ei  = (const int*)d_in[1];     // [2, E]: src row then dst row
    const float* ew  = (const float*)d_in[2];
    const float* W1  = (const float*)d_in[3];
    const float* b1  = (const float*)d_in[4];
    const float* W2  = (const float*)d_in[5];
    const float* b2  = (const float*)d_in[6];
    float* outp = (float*)d_out;

    const int E = in_sizes[1] / 2;
    const int Nn = N_NODES;
    const int* srcv = ei;
    const int* dstv = ei + E;

    // workspace layout
    float* x0   = (float*)d_ws;                         // Nn*NCLASS
    float* bufA = x0 + (size_t)Nn * NCLASS;             // Nn*NCLASS
    float* bufB = bufA + (size_t)Nn * NCLASS;           // Nn*NCLASS
    int* row_ptr = (int*)(bufB + (size_t)Nn * NCLASS);  // Nn+1
    int* fill    = row_ptr + (Nn + 1);                  // Nn (also counts)
    int* col     = fill + Nn;                           // E
    float* wsorted = (float*)(col + E);                 // E
    float* h = bufA;                                    // Nn*NHID overlays bufA+bufB

    // ---- CSR build ----
    hipMemsetAsync(fill, 0, (size_t)Nn * sizeof(int), stream);
    count_kernel<<<(E + 255) / 256, 256, 0, stream>>>(dstv, fill, E);
    scan_kernel<<<1, 1024, 0, stream>>>(fill, row_ptr, fill, Nn);
    scatter_kernel<<<(E + 255) / 256, 256, 0, stream>>>(srcv, dstv, ew, fill, col, wsorted, E);

    // ---- MLP ----
    {
        dim3 g1((NHID + GBN - 1) / GBN, (Nn + GBM - 1) / GBM);
        gemm_bias<<<g1, 256, 0, stream>>>(x, W1, b1, h, Nn, NHID, NFEAT, 1);
        dim3 g2((NCLASS + GBN - 1) / GBN, (Nn + GBM - 1) / GBM);
        gemm_bias<<<g2, 256, 0, stream>>>(h, W2, b2, x0, Nn, NCLASS, NHID, 0);
    }

    // ---- K_HOPS propagation, ping-pong ----
    int grid = (Nn + 3) / 4;
    const float* carry = x0;
    float* dsts[2] = {bufA, bufB};
    for (int k = 0; k < K_HOPS; ++k) {
        float* o = dsts[k & 1];
        hop_kernel<<<grid, 256, 0, stream>>>(carry, x0, row_ptr, col, wsorted, o, Nn);
        carry = o;
    }

    // ---- log_softmax ----
    logsoftmax_kernel<<<grid, 256, 0, stream>>>(carry, outp, Nn);
}

// Round 2
// 1143.433 us; speedup vs baseline: 1.4139x; 1.4139x over previous
//
#include <hip/hip_runtime.h>
#include <hip/hip_bf16.h>
#include <cstdint>
#include <cstddef>

#define N_NODES 100000
#define NFEAT 512
#define NHID 256
#define NCLASS 128
#define K_HOPS 5
#define ALPHA 0.1f

typedef __attribute__((ext_vector_type(8))) short short8v;   // 8 bf16 (4 VGPRs)
typedef __attribute__((ext_vector_type(4))) float f32x4;     // MFMA accumulator

__device__ __forceinline__ unsigned short f2bf(float f) {
    unsigned u = __builtin_bit_cast(unsigned, f);
    u += 0x7FFFu + ((u >> 16) & 1u);      // round-to-nearest-even
    return (unsigned short)(u >> 16);
}

// ---------------------------------------------------------------------------
// CSR build: histogram -> scan -> scatter
// ---------------------------------------------------------------------------

__global__ void count_kernel(const int* __restrict__ dst, int* __restrict__ counts, int E) {
    int i = blockIdx.x * blockDim.x + threadIdx.x;
    if (i < E) atomicAdd(&counts[dst[i]], 1);
}

__global__ __launch_bounds__(1024) void scan_kernel(const int* __restrict__ counts,
                                                    int* __restrict__ row_ptr,
                                                    int* __restrict__ fill, int n) {
    __shared__ int part[1024];
    int tid = threadIdx.x;
    int chunk = (n + 1023) / 1024;
    int beg = tid * chunk;
    int end = beg + chunk; if (end > n) end = n;
    int s = 0;
    for (int i = beg; i < end; ++i) s += counts[i];
    part[tid] = s;
    __syncthreads();
    for (int off = 1; off < 1024; off <<= 1) {
        int v = (tid >= off) ? part[tid - off] : 0;
        __syncthreads();
        part[tid] += v;
        __syncthreads();
    }
    int pre = (tid == 0) ? 0 : part[tid - 1];
    for (int i = beg; i < end; ++i) {
        int c = counts[i];           // read BEFORE overwriting (fill may alias counts)
        row_ptr[i] = pre;
        fill[i] = pre;
        pre += c;
    }
    if (tid == 1023) row_ptr[n] = part[1023];
}

__global__ void scatter_kernel(const int* __restrict__ src, const int* __restrict__ dst,
                               const float* __restrict__ w, int* __restrict__ fill,
                               int* __restrict__ col, float* __restrict__ wsorted, int E) {
    int i = blockIdx.x * blockDim.x + threadIdx.x;
    if (i < E) {
        int d = dst[i];
        int pos = atomicAdd(&fill[d], 1);
        col[pos] = src[i];
        wsorted[pos] = w[i];
    }
}

// ---------------------------------------------------------------------------
// Weight transpose + bf16 convert: Wt[n][k] = bf16(W[k][n])
// ---------------------------------------------------------------------------
__global__ void wtrans_kernel(const float* __restrict__ W, unsigned short* __restrict__ Wt,
                              int K, int N) {
    int idx = blockIdx.x * blockDim.x + threadIdx.x;   // over N*K, k fastest -> coalesced writes
    if (idx >= N * K) return;
    int n = idx / K, k = idx - n * K;
    Wt[idx] = f2bf(W[(size_t)k * N + n]);
}

// ---------------------------------------------------------------------------
// MFMA GEMM, 128x128 tile, 4 waves, 4x4 16x16x32 fragments, BK=32.
// Wave w=(wr,wc) owns 64x64 at (wr*64, wc*64).
//   a-frag: A[row = m*16 + (lane&15)][k = (lane>>4)*8 + j]
//   b-frag: B[k = (lane>>4)*8 + j][col = n*16 + (lane&15)]  (B staged transposed [n][k])
//   acc:    C[row = m*16 + (lane>>4)*4 + reg][col = n*16 + (lane&15)]
// ---------------------------------------------------------------------------

// Layer 1: X f32 [M][512] x W1t bf16 [256][512] -> Hb bf16 [M][256], relu(.+b1)
__global__ __launch_bounds__(256) void gemm1_mfma(const float* __restrict__ X,
                                                  const unsigned short* __restrict__ W1t,
                                                  const float* __restrict__ b1,
                                                  unsigned short* __restrict__ Hb, int M) {
    __shared__ unsigned short As[128 * 32];
    __shared__ unsigned short Bs[128 * 32];
    const int tid = threadIdx.x;
    const int lane = tid & 63;
    const int wv = tid >> 6;
    const int wr = wv >> 1, wc = wv & 1;
    const int brow = blockIdx.y * 128;
    const int bcol = blockIdx.x * 128;

    f32x4 acc[4][4];
#pragma unroll
    for (int m = 0; m < 4; ++m)
#pragma unroll
        for (int n = 0; n < 4; ++n) acc[m][n] = f32x4{0.f, 0.f, 0.f, 0.f};

    for (int k0 = 0; k0 < NFEAT; k0 += 32) {
        // stage A: f32 -> bf16, [m][k] row-major, 16B chunk per (m, kgroup)
#pragma unroll
        for (int cc = 0; cc < 2; ++cc) {
            int c = tid + cc * 256;            // chunk 0..511
            int m = c >> 2, kg = (c & 3) << 3;
            int row = brow + m; if (row > M - 1) row = M - 1;
            const float4 v0 = *(const float4*)&X[(size_t)row * NFEAT + k0 + kg];
            const float4 v1 = *(const float4*)&X[(size_t)row * NFEAT + k0 + kg + 4];
            short8v pk;
            pk[0] = (short)f2bf(v0.x); pk[1] = (short)f2bf(v0.y);
            pk[2] = (short)f2bf(v0.z); pk[3] = (short)f2bf(v0.w);
            pk[4] = (short)f2bf(v1.x); pk[5] = (short)f2bf(v1.y);
            pk[6] = (short)f2bf(v1.z); pk[7] = (short)f2bf(v1.w);
            *(short8v*)&As[c * 8] = pk;
        }
        // stage B: already bf16 + transposed, straight 16B copies
#pragma unroll
        for (int cc = 0; cc < 2; ++cc) {
            int c = tid + cc * 256;
            int n = c >> 2, kg = (c & 3) << 3;
            *(short8v*)&Bs[c * 8] = *(const short8v*)&W1t[(size_t)(bcol + n) * NFEAT + k0 + kg];
        }
        __syncthreads();
        short8v a[4], b[4];
#pragma unroll
        for (int m = 0; m < 4; ++m)
            a[m] = *(const short8v*)&As[((wr * 64 + m * 16 + (lane & 15)) * 4 + (lane >> 4)) * 8];
#pragma unroll
        for (int n = 0; n < 4; ++n)
            b[n] = *(const short8v*)&Bs[((wc * 64 + n * 16 + (lane & 15)) * 4 + (lane >> 4)) * 8];
#pragma unroll
        for (int m = 0; m < 4; ++m)
#pragma unroll
            for (int n = 0; n < 4; ++n)
                acc[m][n] = __builtin_amdgcn_mfma_f32_16x16x32_bf16(a[m], b[n], acc[m][n], 0, 0, 0);
        __syncthreads();
    }

#pragma unroll
    for (int n = 0; n < 4; ++n) {
        int colg = bcol + wc * 64 + n * 16 + (lane & 15);
        float bias = b1[colg];
#pragma unroll
        for (int m = 0; m < 4; ++m) {
#pragma unroll
            for (int r = 0; r < 4; ++r) {
                int rowg = brow + wr * 64 + m * 16 + (lane >> 4) * 4 + r;
                if (rowg < M) {
                    float vl = fmaxf(acc[m][n][r] + bias, 0.f);
                    Hb[(size_t)rowg * NHID + colg] = f2bf(vl);
                }
            }
        }
    }
}

// Layer 2: Hb bf16 [M][256] x W2t bf16 [128][256] -> X0 f32 [M][128], + b2
__global__ __launch_bounds__(256) void gemm2_mfma(const unsigned short* __restrict__ Hb,
                                                  const unsigned short* __restrict__ W2t,
                                                  const float* __restrict__ b2,
                                                  float* __restrict__ X0, int M) {
    __shared__ unsigned short As[128 * 32];
    __shared__ unsigned short Bs[128 * 32];
    const int tid = threadIdx.x;
    const int lane = tid & 63;
    const int wv = tid >> 6;
    const int wr = wv >> 1, wc = wv & 1;
    const int brow = blockIdx.y * 128;

    f32x4 acc[4][4];
#pragma unroll
    for (int m = 0; m < 4; ++m)
#pragma unroll
        for (int n = 0; n < 4; ++n) acc[m][n] = f32x4{0.f, 0.f, 0.f, 0.f};

    for (int k0 = 0; k0 < NHID; k0 += 32) {
#pragma unroll
        for (int cc = 0; cc < 2; ++cc) {
            int c = tid + cc * 256;
            int m = c >> 2, kg = (c & 3) << 3;
            int row = brow + m; if (row > M - 1) row = M - 1;
            *(short8v*)&As[c * 8] = *(const short8v*)&Hb[(size_t)row * NHID + k0 + kg];
        }
#pragma unroll
        for (int cc = 0; cc < 2; ++cc) {
            int c = tid + cc * 256;
            int n = c >> 2, kg = (c & 3) << 3;
            *(short8v*)&Bs[c * 8] = *(const short8v*)&W2t[(size_t)n * NHID + k0 + kg];
        }
        __syncthreads();
        short8v a[4], b[4];
#pragma unroll
        for (int m = 0; m < 4; ++m)
            a[m] = *(const short8v*)&As[((wr * 64 + m * 16 + (lane & 15)) * 4 + (lane >> 4)) * 8];
#pragma unroll
        for (int n = 0; n < 4; ++n)
            b[n] = *(const short8v*)&Bs[((wc * 64 + n * 16 + (lane & 15)) * 4 + (lane >> 4)) * 8];
#pragma unroll
        for (int m = 0; m < 4; ++m)
#pragma unroll
            for (int n = 0; n < 4; ++n)
                acc[m][n] = __builtin_amdgcn_mfma_f32_16x16x32_bf16(a[m], b[n], acc[m][n], 0, 0, 0);
        __syncthreads();
    }

#pragma unroll
    for (int n = 0; n < 4; ++n) {
        int colg = wc * 64 + n * 16 + (lane & 15);   // bcol == 0 (N=128, one col-block)
        float bias = b2[colg];
#pragma unroll
        for (int m = 0; m < 4; ++m) {
#pragma unroll
            for (int r = 0; r < 4; ++r) {
                int rowg = brow + wr * 64 + m * 16 + (lane >> 4) * 4 + r;
                if (rowg < M)
                    X0[(size_t)rowg * NCLASS + colg] = acc[m][n][r] + bias;
            }
        }
    }
}

// ---------------------------------------------------------------------------
// One propagation hop (pull over CSR-by-dst). One wave per node; lanes preload
// up to 64 edges' metadata, broadcast via readlane (SGPR base for the gather).
// FINAL=1 fuses the log-softmax.
// ---------------------------------------------------------------------------
template<int FINAL>
__global__ __launch_bounds__(256) void hop_kernel(const float* __restrict__ carry,
                                                  const float* __restrict__ x0,
                                                  const int* __restrict__ rp,
                                                  const int* __restrict__ col,
                                                  const float* __restrict__ ew,
                                                  float* __restrict__ out, int nnodes) {
    int node = blockIdx.x * 4 + (threadIdx.x >> 6);
    if (node >= nnodes) return;
    int lane = threadIdx.x & 63;
    int e0 = rp[node], e1 = rp[node + 1];

    float a0x = 0.f, a0y = 0.f, a1x = 0.f, a1y = 0.f;
    float a2x = 0.f, a2y = 0.f, a3x = 0.f, a3y = 0.f;

    for (int eb = e0; eb < e1; eb += 64) {
        int nb = e1 - eb; if (nb > 64) nb = 64;
        int cs = 0, wvi = 0;
        if (lane < nb) {
            cs = col[eb + lane];
            wvi = __builtin_bit_cast(int, ew[eb + lane]);
        }
        int j = 0;
        for (; j + 3 < nb; j += 4) {
            int s0 = __builtin_amdgcn_readlane(cs, j);
            int s1 = __builtin_amdgcn_readlane(cs, j + 1);
            int s2 = __builtin_amdgcn_readlane(cs, j + 2);
            int s3 = __builtin_amdgcn_readlane(cs, j + 3);
            float w0 = __builtin_bit_cast(float, __builtin_amdgcn_readlane(wvi, j));
            float w1 = __builtin_bit_cast(float, __builtin_amdgcn_readlane(wvi, j + 1));
            float w2 = __builtin_bit_cast(float, __builtin_amdgcn_readlane(wvi, j + 2));
            float w3 = __builtin_bit_cast(float, __builtin_amdgcn_readlane(wvi, j + 3));
            float2 v0 = ((const float2*)(carry + ((size_t)s0 << 7)))[lane];
            float2 v1 = ((const float2*)(carry + ((size_t)s1 << 7)))[lane];
            float2 v2 = ((const float2*)(carry + ((size_t)s2 << 7)))[lane];
            float2 v3 = ((const float2*)(carry + ((size_t)s3 << 7)))[lane];
            a0x = fmaf(w0, v0.x, a0x); a0y = fmaf(w0, v0.y, a0y);
            a1x = fmaf(w1, v1.x, a1x); a1y = fmaf(w1, v1.y, a1y);
            a2x = fmaf(w2, v2.x, a2x); a2y = fmaf(w2, v2.y, a2y);
            a3x = fmaf(w3, v3.x, a3x); a3y = fmaf(w3, v3.y, a3y);
        }
        for (; j < nb; ++j) {
            int s0 = __builtin_amdgcn_readlane(cs, j);
            float w0 = __builtin_bit_cast(float, __builtin_amdgcn_readlane(wvi, j));
            float2 v0 = ((const float2*)(carry + ((size_t)s0 << 7)))[lane];
            a0x = fmaf(w0, v0.x, a0x); a0y = fmaf(w0, v0.y, a0y);
        }
    }

    size_t base = (size_t)node * NCLASS + lane * 2;
    float2 xv = *(const float2*)&x0[base];
    float vx = (1.f - ALPHA) * (a0x + a1x + a2x + a3x) + ALPHA * xv.x;
    float vy = (1.f - ALPHA) * (a0y + a1y + a2y + a3y) + ALPHA * xv.y;

    if (FINAL) {
        float mx = fmaxf(vx, vy);
#pragma unroll
        for (int off = 32; off; off >>= 1) mx = fmaxf(mx, __shfl_xor(mx, off, 64));
        float se = __expf(vx - mx) + __expf(vy - mx);
#pragma unroll
        for (int off = 32; off; off >>= 1) se += __shfl_xor(se, off, 64);
        float l = mx + __logf(se);
        vx -= l; vy -= l;
    }
    float2 o; o.x = vx; o.y = vy;
    *(float2*)&out[base] = o;
}

// ---------------------------------------------------------------------------

extern "C" void kernel_launch(void* const* d_in, const int* in_sizes, int n_in,
                              void* d_out, int out_size, void* d_ws, size_t ws_size,
                              hipStream_t stream) {
    const float* x   = (const float*)d_in[0];
    const int*   ei  = (const int*)d_in[1];
    const float* ew  = (const float*)d_in[2];
    const float* W1  = (const float*)d_in[3];
    const float* b1  = (const float*)d_in[4];
    const float* W2  = (const float*)d_in[5];
    const float* b2  = (const float*)d_in[6];
    float* outp = (float*)d_out;

    const int E = in_sizes[1] / 2;
    const int Nn = N_NODES;
    const int* srcv = ei;
    const int* dstv = ei + E;

    // workspace layout
    float* x0   = (float*)d_ws;                               // 12.8M f32
    float* bufA = x0 + (size_t)Nn * NCLASS;                   // 12.8M f32
    float* bufB = bufA + (size_t)Nn * NCLASS;                 // 12.8M f32
    unsigned short* hb  = (unsigned short*)bufA;              // overlay: dead before hop 1
    unsigned short* w1t = (unsigned short*)(bufB + (size_t)Nn * NCLASS); // 256x512
    unsigned short* w2t = w1t + NHID * NFEAT;                 // 128x256
    int* row_ptr = (int*)(w2t + NCLASS * NHID);               // Nn+1
    int* fill    = row_ptr + (Nn + 1);                        // Nn (counts)
    int* col     = fill + Nn;                                 // E
    float* wsorted = (float*)(col + E);                       // E

    // ---- CSR build ----
    hipMemsetAsync(fill, 0, (size_t)Nn * sizeof(int), stream);
    count_kernel<<<(E + 255) / 256, 256, 0, stream>>>(dstv, fill, E);
    scan_kernel<<<1, 1024, 0, stream>>>(fill, row_ptr, fill, Nn);
    scatter_kernel<<<(E + 255) / 256, 256, 0, stream>>>(srcv, dstv, ew, fill, col, wsorted, E);

    // ---- weight prep ----
    wtrans_kernel<<<(NHID * NFEAT + 255) / 256, 256, 0, stream>>>(W1, w1t, NFEAT, NHID);
    wtrans_kernel<<<(NCLASS * NHID + 255) / 256, 256, 0, stream>>>(W2, w2t, NHID, NCLASS);

    // ---- MLP (bf16 MFMA) ----
    {
        dim3 g1(NHID / 128, (Nn + 127) / 128);
        gemm1_mfma<<<g1, 256, 0, stream>>>(x, w1t, b1, hb, Nn);
        dim3 g2(1, (Nn + 127) / 128);
        gemm2_mfma<<<g2, 256, 0, stream>>>(hb, w2t, b2, x0, Nn);
    }

    // ---- K_HOPS propagation, ping-pong; last hop fuses log-softmax ----
    int grid = (Nn + 3) / 4;
    const float* carry = x0;
    float* dsts[2] = {bufA, bufB};
    for (int k = 0; k < K_HOPS - 1; ++k) {
        float* o = dsts[k & 1];
        hop_kernel<0><<<grid, 256, 0, stream>>>(carry, x0, row_ptr, col, wsorted, o, Nn);
        carry = o;
    }
    hop_kernel<1><<<grid, 256, 0, stream>>>(carry, x0, row_ptr, col, wsorted, outp, Nn);
}

// Round 3
// 664.896 us; speedup vs baseline: 2.4314x; 1.7197x over previous
//
#include <hip/hip_runtime.h>
#include <hip/hip_bf16.h>
#include <cstdint>
#include <cstddef>

#define N_NODES 100000
#define NFEAT 512
#define NHID 256
#define NCLASS 128
#define K_HOPS 5
#define ALPHA 0.1f

typedef __attribute__((ext_vector_type(8))) short short8v;   // 8 bf16 (4 VGPRs)
typedef __attribute__((ext_vector_type(4))) float f32x4;     // MFMA accumulator

__device__ __forceinline__ unsigned short f2bf(float f) {
    unsigned u = __builtin_bit_cast(unsigned, f);
    u += 0x7FFFu + ((u >> 16) & 1u);      // round-to-nearest-even
    return (unsigned short)(u >> 16);
}
__device__ __forceinline__ float bflo(unsigned u) {
    return __builtin_bit_cast(float, u << 16);
}
__device__ __forceinline__ float bfhi(unsigned u) {
    return __builtin_bit_cast(float, u & 0xFFFF0000u);
}

// ---------------------------------------------------------------------------
// CSR build: histogram -> hierarchical scan -> scatter
// ---------------------------------------------------------------------------

__global__ void count_kernel(const int* __restrict__ dst, int* __restrict__ counts, int E) {
    int i = blockIdx.x * blockDim.x + threadIdx.x;
    if (i < E) atomicAdd(&counts[dst[i]], 1);
}

// P1: block b sums counts[b*1024 .. b*1024+1024) -> partial[b]
__global__ __launch_bounds__(256) void scan_p1(const int* __restrict__ counts,
                                               int* __restrict__ partial, int n) {
    __shared__ int ws[4];
    int b = blockIdx.x, t = threadIdx.x;
    int base = b * 1024 + t * 4;
    int s = 0;
#pragma unroll
    for (int j = 0; j < 4; ++j) {
        int idx = base + j;
        if (idx < n) s += counts[idx];
    }
#pragma unroll
    for (int off = 32; off; off >>= 1) s += __shfl_xor(s, off, 64);
    if ((t & 63) == 0) ws[t >> 6] = s;
    __syncthreads();
    if (t == 0) partial[b] = ws[0] + ws[1] + ws[2] + ws[3];
}

// P2: exclusive scan of partial[nb] in one small block (nb <= 128)
__global__ __launch_bounds__(128) void scan_p2(int* __restrict__ partial, int nb) {
    __shared__ int s[128];
    int t = threadIdx.x;
    int v = (t < nb) ? partial[t] : 0;
    s[t] = v;
    __syncthreads();
    for (int off = 1; off < 128; off <<= 1) {
        int u = (t >= off) ? s[t - off] : 0;
        __syncthreads();
        s[t] += u;
        __syncthreads();
    }
    if (t < nb) partial[t] = (t == 0) ? 0 : s[t - 1];
}

// P3: per-block exclusive scan + global offset; writes row_ptr and fill.
// counts may alias fill (each index read by exactly one thread before write).
__global__ __launch_bounds__(256) void scan_p3(const int* __restrict__ counts,
                                               const int* __restrict__ partial,
                                               int* __restrict__ row_ptr,
                                               int* __restrict__ fill, int n) {
    __shared__ int ts[256];
    int b = blockIdx.x, t = threadIdx.x;
    int base = b * 1024 + t * 4;
    int c[4];
#pragma unroll
    for (int j = 0; j < 4; ++j) {
        int idx = base + j;
        c[j] = (idx < n) ? counts[idx] : 0;
    }
    int s = c[0] + c[1] + c[2] + c[3];
    ts[t] = s;
    __syncthreads();
    for (int off = 1; off < 256; off <<= 1) {
        int v = (t >= off) ? ts[t - off] : 0;
        __syncthreads();
        ts[t] += v;
        __syncthreads();
    }
    int pre = partial[b] + ((t == 0) ? 0 : ts[t - 1]);
#pragma unroll
    for (int j = 0; j < 4; ++j) {
        int idx = base + j;
        if (idx < n) {
            row_ptr[idx] = pre;
            fill[idx] = pre;
            if (idx == n - 1) row_ptr[n] = pre + c[j];
            pre += c[j];
        }
    }
}

__global__ void scatter_kernel(const int* __restrict__ src, const int* __restrict__ dst,
                               const float* __restrict__ w, int* __restrict__ fill,
                               int* __restrict__ col, float* __restrict__ wsorted, int E) {
    int i = blockIdx.x * blockDim.x + threadIdx.x;
    if (i < E) {
        int d = dst[i];
        int pos = atomicAdd(&fill[d], 1);
        col[pos] = src[i];
        wsorted[pos] = w[i];
    }
}

// ---------------------------------------------------------------------------
// Weight transpose + bf16 convert: Wt[n][k] = bf16(W[k][n])
// ---------------------------------------------------------------------------
__global__ void wtrans_kernel(const float* __restrict__ W, unsigned short* __restrict__ Wt,
                              int K, int N) {
    int idx = blockIdx.x * blockDim.x + threadIdx.x;
    if (idx >= N * K) return;
    int n = idx / K, k = idx - n * K;
    Wt[idx] = f2bf(W[(size_t)k * N + n]);
}

// ---------------------------------------------------------------------------
// MFMA GEMM, 128x128 tile, 4 waves, 4x4 16x16x32 fragments, BK=32.
//   a-frag: A[row = m*16 + (lane&15)][k = (lane>>4)*8 + j]
//   b-frag: B[k = (lane>>4)*8 + j][col = n*16 + (lane&15)]  (B staged transposed [n][k])
//   acc:    C[row = m*16 + (lane>>4)*4 + reg][col = n*16 + (lane&15)]
// ---------------------------------------------------------------------------

// Layer 1: X f32 [M][512] x W1t bf16 [256][512] -> Hb bf16 [M][256], relu(.+b1)
__global__ __launch_bounds__(256) void gemm1_mfma(const float* __restrict__ X,
                                                  const unsigned short* __restrict__ W1t,
                                                  const float* __restrict__ b1,
                                                  unsigned short* __restrict__ Hb, int M) {
    __shared__ unsigned short As[128 * 32];
    __shared__ unsigned short Bs[128 * 32];
    const int tid = threadIdx.x;
    const int lane = tid & 63;
    const int wv = tid >> 6;
    const int wr = wv >> 1, wc = wv & 1;
    const int brow = blockIdx.y * 128;
    const int bcol = blockIdx.x * 128;

    f32x4 acc[4][4];
#pragma unroll
    for (int m = 0; m < 4; ++m)
#pragma unroll
        for (int n = 0; n < 4; ++n) acc[m][n] = f32x4{0.f, 0.f, 0.f, 0.f};

    for (int k0 = 0; k0 < NFEAT; k0 += 32) {
#pragma unroll
        for (int cc = 0; cc < 2; ++cc) {
            int c = tid + cc * 256;            // chunk 0..511
            int m = c >> 2, kg = (c & 3) << 3;
            int row = brow + m; if (row > M - 1) row = M - 1;
            const float4 v0 = *(const float4*)&X[(size_t)row * NFEAT + k0 + kg];
            const float4 v1 = *(const float4*)&X[(size_t)row * NFEAT + k0 + kg + 4];
            short8v pk;
            pk[0] = (short)f2bf(v0.x); pk[1] = (short)f2bf(v0.y);
            pk[2] = (short)f2bf(v0.z); pk[3] = (short)f2bf(v0.w);
            pk[4] = (short)f2bf(v1.x); pk[5] = (short)f2bf(v1.y);
            pk[6] = (short)f2bf(v1.z); pk[7] = (short)f2bf(v1.w);
            *(short8v*)&As[c * 8] = pk;
        }
#pragma unroll
        for (int cc = 0; cc < 2; ++cc) {
            int c = tid + cc * 256;
            int n = c >> 2, kg = (c & 3) << 3;
            *(short8v*)&Bs[c * 8] = *(const short8v*)&W1t[(size_t)(bcol + n) * NFEAT + k0 + kg];
        }
        __syncthreads();
        short8v a[4], b[4];
#pragma unroll
        for (int m = 0; m < 4; ++m)
            a[m] = *(const short8v*)&As[((wr * 64 + m * 16 + (lane & 15)) * 4 + (lane >> 4)) * 8];
#pragma unroll
        for (int n = 0; n < 4; ++n)
            b[n] = *(const short8v*)&Bs[((wc * 64 + n * 16 + (lane & 15)) * 4 + (lane >> 4)) * 8];
#pragma unroll
        for (int m = 0; m < 4; ++m)
#pragma unroll
            for (int n = 0; n < 4; ++n)
                acc[m][n] = __builtin_amdgcn_mfma_f32_16x16x32_bf16(a[m], b[n], acc[m][n], 0, 0, 0);
        __syncthreads();
    }

#pragma unroll
    for (int n = 0; n < 4; ++n) {
        int colg = bcol + wc * 64 + n * 16 + (lane & 15);
        float bias = b1[colg];
#pragma unroll
        for (int m = 0; m < 4; ++m) {
#pragma unroll
            for (int r = 0; r < 4; ++r) {
                int rowg = brow + wr * 64 + m * 16 + (lane >> 4) * 4 + r;
                if (rowg < M) {
                    float vl = fmaxf(acc[m][n][r] + bias, 0.f);
                    Hb[(size_t)rowg * NHID + colg] = f2bf(vl);
                }
            }
        }
    }
}

// Layer 2: Hb bf16 [M][256] x W2t bf16 [128][256] -> C0 bf16 [M][128], + b2
__global__ __launch_bounds__(256) void gemm2_mfma(const unsigned short* __restrict__ Hb,
                                                  const unsigned short* __restrict__ W2t,
                                                  const float* __restrict__ b2,
                                                  unsigned short* __restrict__ C0, int M) {
    __shared__ unsigned short As[128 * 32];
    __shared__ unsigned short Bs[128 * 32];
    const int tid = threadIdx.x;
    const int lane = tid & 63;
    const int wv = tid >> 6;
    const int wr = wv >> 1, wc = wv & 1;
    const int brow = blockIdx.y * 128;

    f32x4 acc[4][4];
#pragma unroll
    for (int m = 0; m < 4; ++m)
#pragma unroll
        for (int n = 0; n < 4; ++n) acc[m][n] = f32x4{0.f, 0.f, 0.f, 0.f};

    for (int k0 = 0; k0 < NHID; k0 += 32) {
#pragma unroll
        for (int cc = 0; cc < 2; ++cc) {
            int c = tid + cc * 256;
            int m = c >> 2, kg = (c & 3) << 3;
            int row = brow + m; if (row > M - 1) row = M - 1;
            *(short8v*)&As[c * 8] = *(const short8v*)&Hb[(size_t)row * NHID + k0 + kg];
        }
#pragma unroll
        for (int cc = 0; cc < 2; ++cc) {
            int c = tid + cc * 256;
            int n = c >> 2, kg = (c & 3) << 3;
            *(short8v*)&Bs[c * 8] = *(const short8v*)&W2t[(size_t)n * NHID + k0 + kg];
        }
        __syncthreads();
        short8v a[4], b[4];
#pragma unroll
        for (int m = 0; m < 4; ++m)
            a[m] = *(const short8v*)&As[((wr * 64 + m * 16 + (lane & 15)) * 4 + (lane >> 4)) * 8];
#pragma unroll
        for (int n = 0; n < 4; ++n)
            b[n] = *(const short8v*)&Bs[((wc * 64 + n * 16 + (lane & 15)) * 4 + (lane >> 4)) * 8];
#pragma unroll
        for (int m = 0; m < 4; ++m)
#pragma unroll
            for (int n = 0; n < 4; ++n)
                acc[m][n] = __builtin_amdgcn_mfma_f32_16x16x32_bf16(a[m], b[n], acc[m][n], 0, 0, 0);
        __syncthreads();
    }

#pragma unroll
    for (int n = 0; n < 4; ++n) {
        int colg = wc * 64 + n * 16 + (lane & 15);   // bcol == 0 (N=128)
        float bias = b2[colg];
#pragma unroll
        for (int m = 0; m < 4; ++m) {
#pragma unroll
            for (int r = 0; r < 4; ++r) {
                int rowg = brow + wr * 64 + m * 16 + (lane >> 4) * 4 + r;
                if (rowg < M)
                    C0[(size_t)rowg * NCLASS + colg] = f2bf(acc[m][n][r] + bias);
            }
        }
    }
}

// ---------------------------------------------------------------------------
// One propagation hop (pull over CSR-by-dst), bf16 carry.
// One wave per node; lanes preload up to 64 edges' metadata, broadcast via
// readlane (SGPR gather base). Each lane covers 2 channels (one uint = 2 bf16).
// FINAL=1: fuse log-softmax, write f32 to outf. Else write bf16 to outb.
// ---------------------------------------------------------------------------
template<int FINAL>
__global__ __launch_bounds__(256) void hop_kernel(const unsigned short* __restrict__ carry,
                                                  const unsigned short* __restrict__ c0,
                                                  const int* __restrict__ rp,
                                                  const int* __restrict__ col,
                                                  const float* __restrict__ ew,
                                                  unsigned short* __restrict__ outb,
                                                  float* __restrict__ outf, int nnodes) {
    int node = blockIdx.x * 4 + (threadIdx.x >> 6);
    if (node >= nnodes) return;
    int lane = threadIdx.x & 63;
    int e0 = rp[node], e1 = rp[node + 1];

    float a0x = 0.f, a0y = 0.f, a1x = 0.f, a1y = 0.f;
    float a2x = 0.f, a2y = 0.f, a3x = 0.f, a3y = 0.f;

    for (int eb = e0; eb < e1; eb += 64) {
        int nb = e1 - eb; if (nb > 64) nb = 64;
        int cs = 0, wvi = 0;
        if (lane < nb) {
            cs = col[eb + lane];
            wvi = __builtin_bit_cast(int, ew[eb + lane]);
        }
        int j = 0;
        for (; j + 3 < nb; j += 4) {
            int s0 = __builtin_amdgcn_readlane(cs, j);
            int s1 = __builtin_amdgcn_readlane(cs, j + 1);
            int s2 = __builtin_amdgcn_readlane(cs, j + 2);
            int s3 = __builtin_amdgcn_readlane(cs, j + 3);
            float w0 = __builtin_bit_cast(float, __builtin_amdgcn_readlane(wvi, j));
            float w1 = __builtin_bit_cast(float, __builtin_amdgcn_readlane(wvi, j + 1));
            float w2 = __builtin_bit_cast(float, __builtin_amdgcn_readlane(wvi, j + 2));
            float w3 = __builtin_bit_cast(float, __builtin_amdgcn_readlane(wvi, j + 3));
            unsigned u0 = ((const unsigned*)(carry + ((size_t)s0 << 7)))[lane];
            unsigned u1 = ((const unsigned*)(carry + ((size_t)s1 << 7)))[lane];
            unsigned u2 = ((const unsigned*)(carry + ((size_t)s2 << 7)))[lane];
            unsigned u3 = ((const unsigned*)(carry + ((size_t)s3 << 7)))[lane];
            a0x = fmaf(w0, bflo(u0), a0x); a0y = fmaf(w0, bfhi(u0), a0y);
            a1x = fmaf(w1, bflo(u1), a1x); a1y = fmaf(w1, bfhi(u1), a1y);
            a2x = fmaf(w2, bflo(u2), a2x); a2y = fmaf(w2, bfhi(u2), a2y);
            a3x = fmaf(w3, bflo(u3), a3x); a3y = fmaf(w3, bfhi(u3), a3y);
        }
        for (; j < nb; ++j) {
            int s0 = __builtin_amdgcn_readlane(cs, j);
            float w0 = __builtin_bit_cast(float, __builtin_amdgcn_readlane(wvi, j));
            unsigned u0 = ((const unsigned*)(carry + ((size_t)s0 << 7)))[lane];
            a0x = fmaf(w0, bflo(u0), a0x); a0y = fmaf(w0, bfhi(u0), a0y);
        }
    }

    unsigned ux = ((const unsigned*)(c0 + ((size_t)node << 7)))[lane];
    float vx = (1.f - ALPHA) * (a0x + a1x + a2x + a3x) + ALPHA * bflo(ux);
    float vy = (1.f - ALPHA) * (a0y + a1y + a2y + a3y) + ALPHA * bfhi(ux);

    if (FINAL) {
        float mx = fmaxf(vx, vy);
#pragma unroll
        for (int off = 32; off; off >>= 1) mx = fmaxf(mx, __shfl_xor(mx, off, 64));
        float se = __expf(vx - mx) + __expf(vy - mx);
#pragma unroll
        for (int off = 32; off; off >>= 1) se += __shfl_xor(se, off, 64);
        float l = mx + __logf(se);
        float2 o; o.x = vx - l; o.y = vy - l;
        ((float2*)(outf + ((size_t)node << 7)))[lane] = o;
    } else {
        unsigned o = (unsigned)f2bf(vx) | ((unsigned)f2bf(vy) << 16);
        ((unsigned*)(outb + ((size_t)node << 7)))[lane] = o;
    }
}

// ---------------------------------------------------------------------------

extern "C" void kernel_launch(void* const* d_in, const int* in_sizes, int n_in,
                              void* d_out, int out_size, void* d_ws, size_t ws_size,
                              hipStream_t stream) {
    const float* x   = (const float*)d_in[0];
    const int*   ei  = (const int*)d_in[1];
    const float* ew  = (const float*)d_in[2];
    const float* W1  = (const float*)d_in[3];
    const float* b1  = (const float*)d_in[4];
    const float* W2  = (const float*)d_in[5];
    const float* b2  = (const float*)d_in[6];
    float* outp = (float*)d_out;

    const int E = in_sizes[1] / 2;
    const int Nn = N_NODES;
    const int* srcv = ei;
    const int* dstv = ei + E;
    const size_t NC = (size_t)Nn * NCLASS;   // 12.8M elements

    // workspace layout (all bf16 node buffers are 16B-aligned)
    unsigned short* c0  = (unsigned short*)d_ws;    // bf16 x0 copy     [NC]
    unsigned short* A16 = c0 + NC;                  // ping             [NC]
    unsigned short* B16 = A16 + NC;                 // pong             [NC]
    unsigned short* hb  = A16;                      // H bf16 overlay (Nn*NHID = 2*NC, dead before hops)
    unsigned short* w1t = B16 + NC;                 // 256x512
    unsigned short* w2t = w1t + NHID * NFEAT;       // 128x256
    int* row_ptr = (int*)(w2t + NCLASS * NHID);     // Nn+1
    int* fill    = row_ptr + (Nn + 1);              // Nn (counts)
    int* partial = fill + Nn;                       // 128
    int* col     = partial + 128;                   // E
    float* wsorted = (float*)(col + E);             // E

    const int NB = (Nn + 1023) / 1024;              // 98 scan blocks

    // ---- CSR build ----
    hipMemsetAsync(fill, 0, (size_t)Nn * sizeof(int), stream);
    count_kernel<<<(E + 255) / 256, 256, 0, stream>>>(dstv, fill, E);
    scan_p1<<<NB, 256, 0, stream>>>(fill, partial, Nn);
    scan_p2<<<1, 128, 0, stream>>>(partial, NB);
    scan_p3<<<NB, 256, 0, stream>>>(fill, partial, row_ptr, fill, Nn);
    scatter_kernel<<<(E + 255) / 256, 256, 0, stream>>>(srcv, dstv, ew, fill, col, wsorted, E);

    // ---- weight prep ----
    wtrans_kernel<<<(NHID * NFEAT + 255) / 256, 256, 0, stream>>>(W1, w1t, NFEAT, NHID);
    wtrans_kernel<<<(NCLASS * NHID + 255) / 256, 256, 0, stream>>>(W2, w2t, NHID, NCLASS);

    // ---- MLP (bf16 MFMA) ----
    {
        dim3 g1(NHID / 128, (Nn + 127) / 128);
        gemm1_mfma<<<g1, 256, 0, stream>>>(x, w1t, b1, hb, Nn);
        dim3 g2(1, (Nn + 127) / 128);
        gemm2_mfma<<<g2, 256, 0, stream>>>(hb, w2t, b2, c0, Nn);
    }

    // ---- K_HOPS propagation (bf16 carry), ping-pong; last hop fuses softmax ----
    int grid = (Nn + 3) / 4;
    const unsigned short* carry = c0;
    unsigned short* dsts[2] = {A16, B16};
    for (int k = 0; k < K_HOPS - 1; ++k) {
        unsigned short* o = dsts[k & 1];
        hop_kernel<0><<<grid, 256, 0, stream>>>(carry, c0, row_ptr, col, wsorted, o, nullptr, Nn);
        carry = o;
    }
    hop_kernel<1><<<grid, 256, 0, stream>>>(carry, c0, row_ptr, col, wsorted, nullptr, outp, Nn);
}